// Round 12
// baseline (87.319 us; speedup 1.0000x reference)
//
#include <hip/hip_runtime.h>
#include <hip/hip_bf16.h>

#define B_SZ 4
#define N_SZ 512
#define IN_DIM 128
#define NH 8
#define HD 16
#define SLOPE 0.2f

#define ROWS 32
#define TPB  512
#define GR_STRIDE 20             // 80 B rows: 16B-aligned b128; 8 bank-groups covered per 8 lanes
#define GLS_STRIDE 20

typedef float v2f __attribute__((ext_vector_type(2)));

// ws layout (floats): just gl, gr
#define WS_GL 0
#define WS_GR (NH * B_SZ * N_SZ * HD)                    // 262144
#define WS_TOT (2 * WS_GR)

// ---------------- proj as register-tiled GEMM ----------------
#define PM 32
#define PKC 64
#define AT_S 38
#define BT_S 68

__global__ __launch_bounds__(256) void proj_gemm(
    const float* __restrict__ hin, const float* __restrict__ Wl,
    const float* __restrict__ Wr, float* __restrict__ gl, float* __restrict__ gr)
{
    __shared__ float At[PKC * AT_S];
    __shared__ float Bs[PKC * BT_S];

    int rt = blockIdx.x >> 2;
    int ct = blockIdx.x & 3;
    int side = ct >> 1;
    int headbase = (ct & 1) * 4;
    const float* Wsrc = side ? Wr : Wl;
    int rowbase = rt * PM;

    int t = threadIdx.x;
    int ty = t >> 4;
    int tx = t & 15;

    float acc[2][4] = {{0.f,0.f,0.f,0.f},{0.f,0.f,0.f,0.f}};

    for (int kc = 0; kc < IN_DIM; kc += PKC) {
        __syncthreads();
#pragma unroll
        for (int it = 0; it < 2; ++it) {
            int task = it * 256 + t;
            int r = task >> 4, kq = task & 15;
            float4 v = *(const float4*)&hin[(size_t)(rowbase + r) * IN_DIM + kc + kq * 4];
            At[(kq * 4 + 0) * AT_S + r] = v.x;
            At[(kq * 4 + 1) * AT_S + r] = v.y;
            At[(kq * 4 + 2) * AT_S + r] = v.z;
            At[(kq * 4 + 3) * AT_S + r] = v.w;
        }
#pragma unroll
        for (int it = 0; it < 4; ++it) {
            int task = it * 256 + t;
            int k = task >> 4, cc4 = task & 15;
            int head = headbase + (cc4 >> 2);
            int dq = (cc4 & 3) * 4;
            float4 v = *(const float4*)&Wsrc[head * (IN_DIM * HD) + (kc + k) * HD + dq];
            *(float4*)&Bs[k * BT_S + cc4 * 4] = v;
        }
        __syncthreads();

#pragma unroll 16
        for (int k = 0; k < PKC; ++k) {
            float2 a = *(const float2*)&At[k * AT_S + ty * 2];
            float4 b = *(const float4*)&Bs[k * BT_S + tx * 4];
            acc[0][0] = fmaf(a.x, b.x, acc[0][0]);
            acc[0][1] = fmaf(a.x, b.y, acc[0][1]);
            acc[0][2] = fmaf(a.x, b.z, acc[0][2]);
            acc[0][3] = fmaf(a.x, b.w, acc[0][3]);
            acc[1][0] = fmaf(a.y, b.x, acc[1][0]);
            acc[1][1] = fmaf(a.y, b.y, acc[1][1]);
            acc[1][2] = fmaf(a.y, b.z, acc[1][2]);
            acc[1][3] = fmaf(a.y, b.w, acc[1][3]);
        }
    }

    int head = headbase + (tx >> 2);
    int d4 = (tx & 3) * 4;
    float* g = side ? gr : gl;
#pragma unroll
    for (int r = 0; r < 2; ++r) {
        int row = rowbase + ty * 2 + r;
        int b = row >> 9, i = row & (N_SZ - 1);
        float4 v = {acc[r][0], acc[r][1], acc[r][2], acc[r][3]};
        *(float4*)&g[((size_t)(head * B_SZ + b) * N_SZ + i) * HD + d4] = v;
    }
}

// ---------------- attn: block = (hb, itile of 32 rows); thread owns 2 i-rows ----------------
// score = 0.6*(a.gl_i) + 0.6*(a.gr_j) + 0.4 * sum_d a_d*|gl_id + gr_jd|
__global__ __launch_bounds__(TPB, 4) void attn_kernel(
    const float* __restrict__ gl, const float* __restrict__ gr,
    const float* __restrict__ Wak, const unsigned char* __restrict__ mask,
    float* __restrict__ out)
{
    __shared__ float grs[N_SZ * GR_STRIDE];     // 40960 B (scratch-reused for merge)
    __shared__ float gls[ROWS * GLS_STRIDE];    //  2560 B
    __shared__ float crs[N_SZ];                 //  2048 B

    int bid = blockIdx.x;
    int itile = bid & 15;
    int hb = bid >> 4;                 // head*4 + b
    int head = hb >> 2, b = hb & 3;
    int t = threadIdx.x;

    int ig = t >> 5;                   // 0..15 -> i pair
    int jt = t & 31;                   // 0..31
    int i0 = itile * ROWS + ig * 2;

    // stage g_r (512 x 16) via float4
    const float* grp = gr + (size_t)hb * (N_SZ * HD);
#pragma unroll
    for (int it = 0; it < 4; ++it) {
        int idx4 = it * TPB + t;
        float4 v = ((const float4*)grp)[idx4];
        int j = idx4 >> 2, dq = (idx4 & 3) * 4;
        *(float4*)&grs[j * GR_STRIDE + dq] = v;
    }
    // stage g_l for our 32 rows
    const float* glp = gl + ((size_t)hb * N_SZ + itile * ROWS) * HD;
    gls[(t >> 4) * GLS_STRIDE + (t & 15)] = glp[t];

    // prefetch mask bits: 16 j's per lane for each of the 2 i-rows
    const unsigned char* mrow0 = mask + ((size_t)(b * N_SZ + i0)) * N_SZ;
    unsigned mb0 = 0, mb1 = 0;
#pragma unroll
    for (int jj = 0; jj < N_SZ / 32; ++jj) {
        mb0 |= (mrow0[jj * 32 + jt] ? 1u : 0u) << jj;
        mb1 |= (mrow0[N_SZ + jj * 32 + jt] ? 1u : 0u) << jj;
    }

    __syncthreads();

    const float* ap = Wak + head * HD;   // uniform -> scalar loads

    // crs[j] = 0.6 * (a . gr_j), one j per thread
    {
        const float* r = &grs[t * GR_STRIDE];
        float acc = 0.f;
#pragma unroll
        for (int dd = 0; dd < HD; ++dd) acc = fmaf(ap[dd], r[dd], acc);
        crs[t] = 0.6f * acc;
    }

    v2f glv0[HD / 2], glv1[HD / 2], o0[HD / 2], o1[HD / 2];
    const float* grow0 = &gls[(ig * 2) * GLS_STRIDE];
    const float* grow1 = grow0 + GLS_STRIDE;
#pragma unroll
    for (int e = 0; e < HD / 2; ++e) {
        glv0[e] = *(const v2f*)(grow0 + 2 * e);
        glv1[e] = *(const v2f*)(grow1 + 2 * e);
        o0[e] = (v2f){0.f, 0.f};
        o1[e] = (v2f){0.f, 0.f};
    }
    float cl0, cl1;
    {
        float a0 = 0.f, a1 = 0.f;
#pragma unroll
        for (int dd = 0; dd < HD; ++dd) {
            a0 = fmaf(ap[dd], grow0[dd], a0);
            a1 = fmaf(ap[dd], grow1[dd], a1);
        }
        cl0 = 0.6f * a0; cl1 = 0.6f * a1;
    }

    __syncthreads();                   // crs ready

    float l0 = 0.f, l1 = 0.f;

#pragma unroll 2
    for (int jj = 0; jj < N_SZ / 32; ++jj) {
        int j = jj * 32 + jt;
        const float* r = &grs[j * GR_STRIDE];
        float4 g01 = *(const float4*)(r);
        float4 g23 = *(const float4*)(r + 4);
        float4 g45 = *(const float4*)(r + 8);
        float4 g67 = *(const float4*)(r + 12);
        v2f gj[HD / 2] = {
            (v2f){g01.x, g01.y}, (v2f){g01.z, g01.w},
            (v2f){g23.x, g23.y}, (v2f){g23.z, g23.w},
            (v2f){g45.x, g45.y}, (v2f){g45.z, g45.w},
            (v2f){g67.x, g67.y}, (v2f){g67.z, g67.w}};
        float crj = crs[j];

        float s0a = 0.f, s0b = 0.f, s1a = 0.f, s1b = 0.f;
#pragma unroll
        for (int e = 0; e < HD / 2; ++e) {
            v2f x0 = glv0[e] + gj[e];
            v2f x1 = glv1[e] + gj[e];
            s0a = fmaf(ap[2 * e],     fabsf(x0.x), s0a);
            s0b = fmaf(ap[2 * e + 1], fabsf(x0.y), s0b);
            s1a = fmaf(ap[2 * e],     fabsf(x1.x), s1a);
            s1b = fmaf(ap[2 * e + 1], fabsf(x1.y), s1b);
        }
        float s0 = fminf(fmaf(0.4f, s0a + s0b, cl0 + crj), 80.f);
        float s1 = fminf(fmaf(0.4f, s1a + s1b, cl1 + crj), 80.f);
        if (mb0 & (1u << jj)) s0 = -1e30f;
        if (mb1 & (1u << jj)) s1 = -1e30f;

        float p0 = __expf(s0);
        float p1 = __expf(s1);
        l0 += p0; l1 += p1;
        v2f pv0 = (v2f){p0, p0}, pv1 = (v2f){p1, p1};
#pragma unroll
        for (int e = 0; e < HD / 2; ++e) {
            o0[e] += pv0 * gj[e];
            o1[e] += pv1 * gj[e];
        }
    }

    // partial merge: 2 shuffle rounds (jt groups of 4)
#pragma unroll
    for (int off = 1; off < 4; off <<= 1) {
        l0 += __shfl_xor(l0, off, 64);
        l1 += __shfl_xor(l1, off, 64);
#pragma unroll
        for (int e = 0; e < HD / 2; ++e) {
            v2f q0, q1;
            q0.x = __shfl_xor(o0[e].x, off, 64);
            q0.y = __shfl_xor(o0[e].y, off, 64);
            q1.x = __shfl_xor(o1[e].x, off, 64);
            q1.y = __shfl_xor(o1[e].y, off, 64);
            o0[e] += q0;
            o1[e] += q1;
        }
    }

    __syncthreads();                   // main-loop grs reads done; reuse as scratch

    // scratch layout (in grs): po[32 i][8 g] rows of 20 floats; pl at +5120
    float* po = grs;
    float* pl = grs + 32 * 8 * GR_STRIDE;      // 5120..5375
    if ((jt & 3) == 0) {
        int g = jt >> 2;
        int r0 = (ig * 2) * 8 + g;
        int r1 = r0 + 8;
        float res0[HD], res1[HD];
#pragma unroll
        for (int e = 0; e < HD / 2; ++e) {
            res0[2 * e] = o0[e].x; res0[2 * e + 1] = o0[e].y;
            res1[2 * e] = o1[e].x; res1[2 * e + 1] = o1[e].y;
        }
#pragma unroll
        for (int q = 0; q < 4; ++q) {
            *(float4*)&po[r0 * GR_STRIDE + 4 * q] = *(float4*)&res0[4 * q];
            *(float4*)&po[r1 * GR_STRIDE + 4 * q] = *(float4*)&res1[4 * q];
        }
        pl[r0] = l0;
        pl[r1] = l1;
    }
    __syncthreads();

    // final: thread (i_local, d) sums the 8 group-partials, normalizes, relu, stores
    {
        int il = t >> 4, d = t & 15;
        float os = 0.f, ls = 0.f;
#pragma unroll
        for (int g = 0; g < 8; ++g) {
            os += po[(il * 8 + g) * GR_STRIDE + d];
            ls += pl[il * 8 + g];                  // broadcast across the 16 d-lanes
        }
        int i = itile * ROWS + il;
        out[((size_t)(b * N_SZ + i)) * (NH * HD) + head * HD + d] =
            fmaxf(os / ls, 0.f);
    }
}

// ---------------- fallback: fused kernel (no workspace) ----------------
__global__ __launch_bounds__(TPB) void gatv2_fused(
    const float* __restrict__ hin, const unsigned char* __restrict__ mask,
    const float* __restrict__ Wl, const float* __restrict__ Wr,
    const float* __restrict__ Wak, float* __restrict__ out)
{
    __shared__ float wrs[IN_DIM * HD];
    __shared__ float hsh[32][IN_DIM + 1];
    __shared__ float grs[N_SZ * 18];
    __shared__ float gls[32][HD];

    int bid = blockIdx.x;
    int itile = bid & 15;
    int hb = bid >> 4;
    int head = hb >> 2, b = hb & 3;
    int t = threadIdx.x;

    int jl = t >> 4;
    int d  = t & 15;

    for (int idx = t; idx < IN_DIM * HD; idx += TPB)
        wrs[idx] = Wr[head * IN_DIM * HD + idx];

    const float* hb_base = hin + (size_t)b * N_SZ * IN_DIM;
    const float* wlcol = Wl + head * IN_DIM * HD + d;

    for (int c = 0; c < N_SZ / 32; ++c) {
        __syncthreads();
        const float* hc = hb_base + (size_t)c * 32 * IN_DIM;
        for (int idx = t; idx < 32 * IN_DIM; idx += TPB)
            hsh[idx >> 7][idx & 127] = hc[idx];
        __syncthreads();

        float acc = 0.f;
#pragma unroll 16
        for (int k = 0; k < IN_DIM; ++k)
            acc = fmaf(hsh[jl][k], wrs[k * HD + d], acc);
        grs[(c * 32 + jl) * 18 + d] = acc;

        if (c == itile) {
            float accl = 0.f;
#pragma unroll 16
            for (int k = 0; k < IN_DIM; ++k)
                accl = fmaf(hsh[jl][k], wlcol[k * HD], accl);
            gls[jl][d] = accl;
        }
    }
    __syncthreads();

    int il = jl, jt = d;
    int i = itile * 32 + il;

    float glv[HD], avv[HD];
#pragma unroll
    for (int dd = 0; dd < HD; ++dd) glv[dd] = gls[il][dd];
    const float* ap = Wak + head * HD;
#pragma unroll
    for (int dd = 0; dd < HD; ++dd) avv[dd] = ap[dd];

    const unsigned char* mrow = mask + ((size_t)(b * N_SZ + i)) * N_SZ;

    float m = -1e30f, l = 0.f;
    float o[HD];
#pragma unroll
    for (int dd = 0; dd < HD; ++dd) o[dd] = 0.f;

    for (int jj = 0; jj < N_SZ / 16; ++jj) {
        int j = jj * 16 + jt;
        const float* r = &grs[j * 18];
        float gj[HD];
#pragma unroll
        for (int e = 0; e < HD / 2; ++e) {
            float2 v = *(const float2*)(r + 2 * e);
            gj[2 * e] = v.x; gj[2 * e + 1] = v.y;
        }

        float s = 0.f;
#pragma unroll
        for (int dd = 0; dd < HD; ++dd) {
            float x = glv[dd] + gj[dd];
            float lr = fmaxf(x, SLOPE * x);
            s = fmaf(avv[dd], lr, s);
        }
        if (mrow[j]) s = -1e30f;

        float mn = fmaxf(m, s);
        float cc = __expf(m - mn);
        float p = __expf(s - mn);
        l = fmaf(l, cc, p);
#pragma unroll
        for (int dd = 0; dd < HD; ++dd)
            o[dd] = fmaf(o[dd], cc, p * gj[dd]);
        m = mn;
    }

#pragma unroll
    for (int off = 1; off < 16; off <<= 1) {
        float mo = __shfl_xor(m, off, 64);
        float lo = __shfl_xor(l, off, 64);
        float mn = fmaxf(m, mo);
        float c1 = __expf(m - mn), c2 = __expf(mo - mn);
        l = l * c1 + lo * c2;
#pragma unroll
        for (int dd = 0; dd < HD; ++dd)
            o[dd] = o[dd] * c1 + __shfl_xor(o[dd], off, 64) * c2;
        m = mn;
    }

    if (jt == 0) {
        float inv = 1.f / l;
        float res[HD];
#pragma unroll
        for (int dd = 0; dd < HD; ++dd)
            res[dd] = fmaxf(o[dd] * inv, 0.f);
        float* op = out + ((size_t)(b * N_SZ + i)) * (NH * HD) + head * HD;
#pragma unroll
        for (int e = 0; e < HD / 4; ++e)
            *(float4*)(op + 4 * e) = *(float4*)(res + 4 * e);
    }
}

extern "C" void kernel_launch(void* const* d_in, const int* in_sizes, int n_in,
                              void* d_out, int out_size, void* d_ws, size_t ws_size,
                              hipStream_t stream) {
    const float* hin = (const float*)d_in[0];
    const unsigned char* mask = (const unsigned char*)d_in[1];
    const float* Wl = (const float*)d_in[2];
    const float* Wr = (const float*)d_in[3];
    const float* Wak = (const float*)d_in[4];
    float* out = (float*)d_out;
    (void)in_sizes; (void)n_in; (void)out_size;

    const size_t need = (size_t)WS_TOT * sizeof(float);   // 2 MB

    if (ws_size >= need && d_ws != nullptr) {
        float* ws = (float*)d_ws;
        float* gl = ws + WS_GL;
        float* gr = ws + WS_GR;
        proj_gemm<<<(B_SZ * N_SZ / PM) * 4, 256, 0, stream>>>(hin, Wl, Wr, gl, gr);
        attn_kernel<<<NH * B_SZ * (N_SZ / ROWS), TPB, 0, stream>>>(
            gl, gr, Wak, mask, out);
    } else {
        gatv2_fused<<<NH * B_SZ * (N_SZ / 32), TPB, 0, stream>>>(
            hin, mask, Wl, Wr, Wak, out);
    }
}